// Round 1
// baseline (112.751 us; speedup 1.0000x reference)
//
#include <hip/hip_runtime.h>
#include <math.h>

#define BB 16
#define CC 6
#define QQ 256
#define TT 256
#define DD 256
#define NPAIR 15                      // C*(C-1)/2 for C=6
#define NBC (BB * CC)                 // 96
#define BIGB (NBC * 8)                // 768  blocks [0, 768)      — 2048 float4/block
#define CONSB (BB * NPAIR * 4)        // 960  blocks [768, 1728)
#define PACKB NBC                     // 96   blocks [1728, 1824)
#define MAIN_BLOCKS (BIGB + CONSB + PACKB)  // 1824

// R10 (this round): big phase FIRST so HBM streaming starts at t=0; wave-level
// ballot fmt-detect (drops 2 barriers/block in all 1824 blocks); fused dual
// pack in cons blocks (6 barriers -> 3); skip assoc loads for !cam big blocks;
// nontemporal tok loads (zero reuse -> keep L2/L3 for assoc cons re-reads);
// k_fin single-pass 9-value reduction (18 barriers -> 2).
//
// ws layout (bytes) — disjoint plain stores only; consumed by k_fin across the
// kernel boundary. (R4: device __threadfence = L2 writeback per block.
// R5: same-line data atomics from 2.5k blocks serialize, +35us.
// R9: single-address ticket atomic = 1728 serialized RMWs, +7us.
// Disjoint stores + kernel boundary is the free publication path on gfx950.)
//   [0,     3072)  packPart float[96*8]   (score,box,pair,qv,cam per bc)
//   [4096, 10240)  bigPart  float[768*2]  (ss, ent per block)
//   [16384,24064)  consPart float[960*2]  (cons, nval per block)

typedef float f4 __attribute__((ext_vector_type(4)));

__device__ __forceinline__ float block_sum256(float v, float* s_red) {
    #pragma unroll
    for (int off = 32; off > 0; off >>= 1) v += __shfl_xor(v, off, 64);
    __syncthreads();
    if ((threadIdx.x & 63) == 0) s_red[threadIdx.x >> 6] = v;
    __syncthreads();
    return s_red[0] + s_red[1] + s_red[2] + s_red[3];
}

// two values reduced with a single pair of barriers
__device__ __forceinline__ float2 block_sum256x2(float a, float b, float2* s_red2) {
    #pragma unroll
    for (int off = 32; off > 0; off >>= 1) {
        a += __shfl_xor(a, off, 64);
        b += __shfl_xor(b, off, 64);
    }
    __syncthreads();
    if ((threadIdx.x & 63) == 0) s_red2[threadIdx.x >> 6] = make_float2(a, b);
    __syncthreads();
    float2 r;
    r.x = s_red2[0].x + s_red2[1].x + s_red2[2].x + s_red2[3].x;
    r.y = s_red2[0].y + s_red2[1].y + s_red2[2].y + s_red2[3].y;
    return r;
}

// four values, one barrier pair
__device__ __forceinline__ float4 block_sum256x4(float a, float b, float c,
                                                 float d, float4* s_red4) {
    #pragma unroll
    for (int off = 32; off > 0; off >>= 1) {
        a += __shfl_xor(a, off, 64);
        b += __shfl_xor(b, off, 64);
        c += __shfl_xor(c, off, 64);
        d += __shfl_xor(d, off, 64);
    }
    __syncthreads();
    if ((threadIdx.x & 63) == 0) s_red4[threadIdx.x >> 6] = make_float4(a, b, c, d);
    __syncthreads();
    float4 r;
    r.x = s_red4[0].x + s_red4[1].x + s_red4[2].x + s_red4[3].x;
    r.y = s_red4[0].y + s_red4[1].y + s_red4[2].y + s_red4[3].y;
    r.z = s_red4[0].z + s_red4[1].z + s_red4[2].z + s_red4[3].z;
    r.w = s_red4[0].w + s_red4[1].w + s_red4[2].w + s_red4[3].w;
    return r;
}

__device__ __forceinline__ int read_bool(const void* p, int idx, int fmt) {
    if (fmt == 2) return ((const float*)p)[idx] != 0.0f;
    if (fmt == 1) return ((const unsigned char*)p)[idx] != 0;
    return ((const int*)p)[idx] != 0;
}

// Wave-uniform bool-storage-format detection from the first 1024 bytes of
// target_mask (valid window in all 3 formats; L2-hot; every wave reads the
// SAME window via lane-indexing so the decision is block-uniform). No
// barriers, no shared atomics. 2=f32, 1=u8, 0=i32.
//   f32 bools: ~50% of 256 words have high byte 0x3F (1.0f)  -> cf ~ 128 > 16
//   u8  bools: high-byte never 0x3F, misaligned bytes nonzero -> cm > 0
//   i32 bools: words are 0/1 -> cf = 0, cm = 0
__device__ __forceinline__ int detect_fmt_wave(const void* tm_raw) {
    const int lane = threadIdx.x & 63;
    uint4 w = ((const uint4*)tm_raw)[lane];
    unsigned long long f0 = __ballot((w.x >> 24) == 0x3Fu);
    unsigned long long f1 = __ballot((w.y >> 24) == 0x3Fu);
    unsigned long long f2 = __ballot((w.z >> 24) == 0x3Fu);
    unsigned long long f3 = __ballot((w.w >> 24) == 0x3Fu);
    int cf = __popcll(f0) + __popcll(f1) + __popcll(f2) + __popcll(f3);
    unsigned long long m0 = __ballot((w.x & 0xFFFFFF00u) != 0u);
    unsigned long long m1 = __ballot((w.y & 0xFFFFFF00u) != 0u);
    unsigned long long m2 = __ballot((w.z & 0xFFFFFF00u) != 0u);
    unsigned long long m3 = __ballot((w.w & 0xFFFFFF00u) != 0u);
    int cm = __popcll(m0) | __popcll(m1) | __popcll(m2) | __popcll(m3);
    return (cf > 16) ? 2 : ((cm > 0) ? 1 : 0);
}

// Fused stable targets-first pack of cameras bc_c and bc_d in one scan pass
// (3 barriers instead of 6). s_tmp is 2*QQ scratch; outputs in s_qc/s_qd.
__device__ __forceinline__ void block_pack2(const void* tm_raw,
                                            const int* __restrict__ ids,
                                            int bc_c, int bc_d, int fmt,
                                            int cam_c, int cam_d,
                                            int* s_tmp, int* s_wsum,
                                            int* s_qc, int* s_qd,
                                            int& count_c, int& count_d) {
    const int t = threadIdx.x, lane = t & 63, wv = t >> 6;
    const int tmc = read_bool(tm_raw, bc_c * QQ + t, fmt);
    const int tmd = read_bool(tm_raw, bc_d * QQ + t, fmt);
    int vc = tmc, vd = tmd;
    #pragma unroll
    for (int off = 1; off < 64; off <<= 1) {
        int uc = __shfl_up(vc, off, 64);
        int ud = __shfl_up(vd, off, 64);
        if (lane >= off) { vc += uc; vd += ud; }
    }
    if (lane == 63) { s_wsum[wv] = vc; s_wsum[4 + wv] = vd; }
    __syncthreads();
    count_c = s_wsum[0] + s_wsum[1] + s_wsum[2] + s_wsum[3];
    count_d = s_wsum[4] + s_wsum[5] + s_wsum[6] + s_wsum[7];
    int woc = 0, wod = 0;
    #pragma unroll
    for (int k = 0; k < 3; k++) {
        if (k < wv) { woc += s_wsum[k]; wod += s_wsum[4 + k]; }
    }
    const int exc = woc + vc - tmc;
    const int exd = wod + vd - tmd;
    const int rc = tmc ? exc : (count_c + (t - exc));   // stable partition rank
    const int rd = tmd ? exd : (count_d + (t - exd));
    s_tmp[rc] = ids[bc_c * QQ + t];
    s_tmp[QQ + rd] = ids[bc_d * QQ + t];
    __syncthreads();
    s_qc[t] = (t < count_c && cam_c) ? s_tmp[t] : -1;
    s_qd[t] = (t < count_d && cam_d) ? s_tmp[QQ + t] : -1;
    __syncthreads();
}

// ---------------------------------------------------------------------------
// Kernel 1: EVERYTHING except the final scalar combine, one dispatch:
//   [0, 768):     det_norm ss + cam-masked entropy (2048-float4 chunks)
//   [768, 1728):  consistency term (pack recomputed locally — no dependency)
//   [1728, 1824): per-(b,c) pack losses (score/box/pair)
// ---------------------------------------------------------------------------
__global__ __launch_bounds__(256)
void k_main(const f4* __restrict__ tok,
            const float* __restrict__ assoc,
            const float* __restrict__ det_scores,
            const float* __restrict__ det_boxes,
            const float* __restrict__ boxes,
            const void* __restrict__ cam_raw,
            const void* __restrict__ tm_raw,
            const int* __restrict__ ids,
            const int* __restrict__ img_h_p,
            const int* __restrict__ img_w_p,
            float* __restrict__ packPart,
            float* __restrict__ bigPart,
            float* __restrict__ consPart) {
    const int blk = blockIdx.x;
    const int t = threadIdx.x, lane = t & 63, wv = t >> 6;
    __shared__ float2 s_red2[4];

    if (blk < BIGB) {
        // ---- big phase: 2048 float4s of tok & assoc ----
        const int bb = blk;
        const int bc = bb >> 3;
        const long base = (long)bc * 16384 + (long)(bb & 7) * 2048 + t;
        const f4* asc = (const f4*)assoc;
        const int fmt = detect_fmt_wave(tm_raw);
        const int cam = read_bool(cam_raw, bc, fmt);

        float ss = 0.0f, ent = 0.0f;
        #pragma unroll
        for (int h = 0; h < 2; h++) {
            const long o = base + h * 1024;
            // tok has zero reuse anywhere: nontemporal, keep L2/L3 for assoc
            f4 t0 = __builtin_nontemporal_load(&tok[o]);
            f4 t1 = __builtin_nontemporal_load(&tok[o + 256]);
            f4 t2 = __builtin_nontemporal_load(&tok[o + 512]);
            f4 t3 = __builtin_nontemporal_load(&tok[o + 768]);
            ss += t0.x * t0.x + t0.y * t0.y + t0.z * t0.z + t0.w * t0.w
                + t1.x * t1.x + t1.y * t1.y + t1.z * t1.z + t1.w * t1.w
                + t2.x * t2.x + t2.y * t2.y + t2.z * t2.z + t2.w * t2.w
                + t3.x * t3.x + t3.y * t3.y + t3.z * t3.z + t3.w * t3.w;
            if (cam) {                            // block-uniform branch
                f4 a0 = asc[o], a1 = asc[o + 256], a2 = asc[o + 512], a3 = asc[o + 768];
                ent -= a0.x * __logf(fmaxf(a0.x, 1e-8f)) + a0.y * __logf(fmaxf(a0.y, 1e-8f))
                     + a0.z * __logf(fmaxf(a0.z, 1e-8f)) + a0.w * __logf(fmaxf(a0.w, 1e-8f));
                ent -= a1.x * __logf(fmaxf(a1.x, 1e-8f)) + a1.y * __logf(fmaxf(a1.y, 1e-8f))
                     + a1.z * __logf(fmaxf(a1.z, 1e-8f)) + a1.w * __logf(fmaxf(a1.w, 1e-8f));
                ent -= a2.x * __logf(fmaxf(a2.x, 1e-8f)) + a2.y * __logf(fmaxf(a2.y, 1e-8f))
                     + a2.z * __logf(fmaxf(a2.z, 1e-8f)) + a2.w * __logf(fmaxf(a2.w, 1e-8f));
                ent -= a3.x * __logf(fmaxf(a3.x, 1e-8f)) + a3.y * __logf(fmaxf(a3.y, 1e-8f))
                     + a3.z * __logf(fmaxf(a3.z, 1e-8f)) + a3.w * __logf(fmaxf(a3.w, 1e-8f));
            }
        }
        float2 r = block_sum256x2(ss, ent, s_red2);
        if (t == 0) { bigPart[bb * 2] = r.x; bigPart[bb * 2 + 1] = r.y; }

    } else if (blk < BIGB + CONSB) {
        // ---- cons phase: one block per (b, pair, qgroup-of-64) ----
        const int cb = blk - BIGB;
        const int qg = cb & 3;
        const int bp = cb >> 2;             // b*NPAIR + pair
        const int b = bp / NPAIR;
        int pi = bp % NPAIR;
        int c = 0, d = 1;
        {
            int k = pi;
            for (c = 0; c < CC - 1; c++) {
                int span = CC - 1 - c;
                if (k < span) { d = c + 1 + k; break; }
                k -= span;
            }
        }
        __shared__ int s_tmp[2 * QQ], s_qc[QQ], s_qd[QQ], s_wsum[8];
        const int fmt = detect_fmt_wave(tm_raw);
        const int cam_c = read_bool(cam_raw, b * CC + c, fmt);
        const int cam_d = read_bool(cam_raw, b * CC + d, fmt);
        int count_c, count_d;
        block_pack2(tm_raw, ids, b * CC + c, b * CC + d, fmt, cam_c, cam_d,
                    s_tmp, s_wsum, s_qc, s_qd, count_c, count_d);

        const int qd0 = s_qd[lane];
        const int qd1 = s_qd[64 + lane];
        const int qd2 = s_qd[128 + lane];
        const int qd3 = s_qd[192 + lane];
        int idarr[16];
        #pragma unroll
        for (int qi = 0; qi < 16; qi++) idarr[qi] = s_qc[qg * 64 + wv * 16 + qi];

        const f4* assoc_c = (const f4*)(assoc + (size_t)(b * CC + c) * QQ * TT);
        const f4* assoc_d = (const f4*)(assoc + (size_t)(b * CC + d) * QQ * TT);

        float tot = 0.0f, nval = 0.0f;
        #pragma unroll 4
        for (int qi = 0; qi < 16; qi++) {
            const int id = idarr[qi];           // wave-uniform
            if (id < 0) continue;
            unsigned long long m0 = __ballot(qd0 == id);
            unsigned long long m1 = __ballot(qd1 == id);
            unsigned long long m2 = __ballot(qd2 == id);
            unsigned long long m3 = __ballot(qd3 == id);
            int cnt = __popcll(m0) + __popcll(m1) + __popcll(m2) + __popcll(m3);
            if (cnt == 0) continue;
            const int q = qg * 64 + wv * 16 + qi;
            f4 r = assoc_c[(size_t)q * (TT / 4) + lane];
            float ax = 0.0f, ay = 0.0f, az = 0.0f, aw = 0.0f;
            unsigned long long mm[4] = {m0, m1, m2, m3};
            #pragma unroll
            for (int kk = 0; kk < 4; kk++) {
                unsigned long long m = mm[kk];
                while (m) {
                    int p = kk * 64 + __builtin_ctzll(m);
                    m &= m - 1;
                    f4 vv = assoc_d[(size_t)p * (TT / 4) + lane];
                    ax += vv.x; ay += vv.y; az += vv.z; aw += vv.w;
                }
            }
            float inv = 1.0f / (float)cnt;
            float dx = r.x - ax * inv, dy = r.y - ay * inv;
            float dz = r.z - az * inv, dw = r.w - aw * inv;
            tot += dx * dx + dy * dy + dz * dz + dw * dw;
            nval += 1.0f;
        }
        float2 r2 = block_sum256x2(tot, nval, s_red2);
        if (t == 0) {
            consPart[cb * 2] = r2.x * (1.0f / TT);
            consPart[cb * 2 + 1] = r2.y;
        }

    } else {
        // ---- pack-loss phase: one block per (b,c) ----
        const int bc = blk - (BIGB + CONSB);
        __shared__ int s_sids[QQ], s_wsum[4];
        __shared__ float4 s_red4[4];
        const int fmt = detect_fmt_wave(tm_raw);
        const int cam = read_bool(cam_raw, bc, fmt);

        const int tm = read_bool(tm_raw, bc * QQ + t, fmt);
        int v = tm;
        #pragma unroll
        for (int off = 1; off < 64; off <<= 1) {
            int u = __shfl_up(v, off, 64);
            if (lane >= off) v += u;
        }
        if (lane == 63) s_wsum[wv] = v;
        __syncthreads();
        const int count = s_wsum[0] + s_wsum[1] + s_wsum[2] + s_wsum[3];
        int woff = 0;
        #pragma unroll
        for (int k = 0; k < 3; k++) woff += (k < wv) ? s_wsum[k] : 0;
        const int excl = woff + v - tm;                      // exclusive scan of tm
        const int rank = tm ? excl : (count + (t - excl));   // stable partition rank
        s_sids[rank] = ids[bc * QQ + t];
        __syncthreads();

        const int j = t;                       // packed slot for score/pair
        const int qv = (j < count) && cam;
        const int qid = qv ? s_sids[j] : -1;

        float score_sum = 0.0f, box_sum = 0.0f, pair_sum = 0.0f;
        if (cam) {
            float p = det_scores[(size_t)bc * QQ + j];
            p = fminf(fmaxf(p, 1e-6f), 1.0f - 1e-6f);
            score_sum = (j < count) ? -__logf(p) : -__logf(1.0f - p);
        }
        if (qv) {
            int slot = qid & (TT - 1);
            float a = assoc[((size_t)bc * QQ + j) * TT + slot];
            pair_sum = -__logf(fmaxf(a, 1e-8f));
        }
        if (tm && cam) {
            const int jj = rank;               // packed slot of original query t
            const float iw = (float)img_w_p[0], ih = (float)img_h_p[0];
            const float* bx = boxes + ((size_t)bc * QQ + t) * 4;
            const float* db = det_boxes + ((size_t)bc * QQ + jj) * 4;
            float b0 = fminf(fmaxf(bx[0] / iw, 0.0f), 1.0f);
            float b1 = fminf(fmaxf(bx[1] / ih, 0.0f), 1.0f);
            float b2 = fminf(fmaxf(bx[2] / iw, 0.0f), 1.0f);
            float b3 = fminf(fmaxf(bx[3] / ih, 0.0f), 1.0f);
            box_sum = fabsf(db[0] - b0) + fabsf(db[1] - b1) +
                      fabsf(db[2] - b2) + fabsf(db[3] - b3);
        }
        float4 r = block_sum256x4(score_sum, box_sum, pair_sum, 0.0f, s_red4);
        if (t == 0) {
            float* row = packPart + bc * 8;
            row[0] = r.x; row[1] = r.y; row[2] = r.z;
            row[3] = cam ? (float)count : 0.0f;
            row[4] = (float)cam;
        }
    }
}

// ---------------------------------------------------------------------------
// Kernel 2: finalize — reduce all partial arrays (~17 KB, L2-hot), 1 block.
// Single-pass 9-value reduction: one barrier pair instead of 18.
// ---------------------------------------------------------------------------
__global__ __launch_bounds__(256)
void k_fin(const float* __restrict__ packPart, const float2* __restrict__ bigPart,
           const float2* __restrict__ consPart, float* __restrict__ out) {
    const int t = threadIdx.x, lane = t & 63, wv = t >> 6;
    __shared__ float s_r[4][9];
    float vals[9];
    #pragma unroll
    for (int k = 0; k < 9; k++) vals[k] = 0.0f;
    if (t < NBC) {
        const float* row = packPart + t * 8;
        vals[0] = row[0]; vals[1] = row[1]; vals[2] = row[2];
        vals[3] = row[3]; vals[4] = row[4];
    }
    #pragma unroll
    for (int k = 0; k < BIGB / 256; k++) {
        float2 v = bigPart[k * 256 + t];
        vals[5] += v.x; vals[6] += v.y;
    }
    for (int i = t; i < CONSB; i += 256) {
        float2 v = consPart[i];
        vals[7] += v.x; vals[8] += v.y;
    }
    #pragma unroll
    for (int off = 32; off > 0; off >>= 1) {
        #pragma unroll
        for (int k = 0; k < 9; k++) vals[k] += __shfl_xor(vals[k], off, 64);
    }
    if (lane == 0) {
        #pragma unroll
        for (int k = 0; k < 9; k++) s_r[wv][k] = vals[k];
    }
    __syncthreads();
    if (t == 0) {
        float sc   = s_r[0][0] + s_r[1][0] + s_r[2][0] + s_r[3][0];
        float bx   = s_r[0][1] + s_r[1][1] + s_r[2][1] + s_r[3][1];
        float pr   = s_r[0][2] + s_r[1][2] + s_r[2][2] + s_r[3][2];
        float qv   = s_r[0][3] + s_r[1][3] + s_r[2][3] + s_r[3][3];
        float cm   = s_r[0][4] + s_r[1][4] + s_r[2][4] + s_r[3][4];
        float ss   = s_r[0][5] + s_r[1][5] + s_r[2][5] + s_r[3][5];
        float ent  = s_r[0][6] + s_r[1][6] + s_r[2][6] + s_r[3][6];
        float cons = s_r[0][7] + s_r[1][7] + s_r[2][7] + s_r[3][7];
        float nval = s_r[0][8] + s_r[1][8] + s_r[2][8] + s_r[3][8];
        float det_norm = ss / (float)((long)BB * CC * QQ * DD);
        float denom_cam = fmaxf(cm * (float)QQ, 1.0f);
        float score_loss = sc / denom_cam;
        float box_loss = bx / fmaxf(4.0f * qv, 1.0f);
        float det_sup = score_loss + box_loss;
        float ent_loss = ent / denom_cam;
        float pair_loss = pr / fmaxf(qv, 1.0f);
        float cons_loss = cons / fmaxf(nval, 1.0f);
        out[0] = det_norm + det_sup + ent_loss + pair_loss + cons_loss;
        out[1] = det_norm;
        out[2] = det_sup;
        out[3] = ent_loss;
        out[4] = pair_loss;
        out[5] = cons_loss;
    }
}

extern "C" void kernel_launch(void* const* d_in, const int* in_sizes, int n_in,
                              void* d_out, int out_size, void* d_ws, size_t ws_size,
                              hipStream_t stream) {
    const float* det_tokens = (const float*)d_in[0];
    const float* det_scores = (const float*)d_in[1];
    const float* det_boxes  = (const float*)d_in[2];
    const float* assoc      = (const float*)d_in[3];
    const float* boxes      = (const float*)d_in[4];
    const void*  cam_raw    = d_in[5];
    const void*  tm_raw     = d_in[6];
    const int*   ids        = (const int*)d_in[7];
    const int*   img_h      = (const int*)d_in[8];
    const int*   img_w      = (const int*)d_in[9];

    char* ws = (char*)d_ws;
    float* packPart = (float*)(ws + 0);
    float* bigPart  = (float*)(ws + 4096);
    float* consPart = (float*)(ws + 16384);

    k_main<<<MAIN_BLOCKS, 256, 0, stream>>>((const f4*)det_tokens, assoc,
                                            det_scores, det_boxes, boxes,
                                            cam_raw, tm_raw, ids, img_h, img_w,
                                            packPart, bigPart, consPart);
    k_fin<<<1, 256, 0, stream>>>(packPart, (const float2*)bigPart,
                                 (const float2*)consPart, (float*)d_out);
}